// Round 3
// baseline (188.039 us; speedup 1.0000x reference)
//
#include <hip/hip_runtime.h>
#include <hip/hip_bf16.h>
#include <float.h>

// x:(10,64,128,256) f32, record_len=[5,5], pairwise_t_matrix:(2,5,5,2,3) f32,
// indicator:(10,) i32.  Output: (2,64,128,256) f32.
constexpr int C  = 64;
constexpr int H  = 128;
constexpr int W  = 256;
constexpr int HW = H * W;

typedef __attribute__((ext_vector_type(8))) unsigned short ushort8;

__device__ __forceinline__ unsigned short f2bf(float f) {
  __hip_bfloat16 h = __float2bfloat16(f);
  return *reinterpret_cast<unsigned short*>(&h);
}

// ---------------------------------------------------------------------------
// Transpose all 10 agents: x[a][c][p] f32 -> xt[a][p][c] bf16.
// 64ch x 64px tile/block; float4 loads, ushort8 (16B) fully-contiguous stores.
// ---------------------------------------------------------------------------
__global__ __launch_bounds__(256) void transpose_cp(
    const float* __restrict__ x, __hip_bfloat16* __restrict__ xt) {
  __shared__ float tile[64][65];
  int blk = blockIdx.x;          // 0..5119
  int a   = blk >> 9;            // agent 0..9
  int p0  = (blk & 511) << 6;    // pixel base
  int tid = threadIdx.x;
  const float* src = x + (size_t)a * C * HW + p0;
  int row = tid >> 4;            // 0..15
  int px4 = (tid & 15) << 2;     // 0,4,...,60
#pragma unroll
  for (int i = 0; i < 4; ++i) {
    int c = i * 16 + row;
    const float4 v = *reinterpret_cast<const float4*>(src + (size_t)c * HW + px4);
    tile[c][px4 + 0] = v.x; tile[c][px4 + 1] = v.y;
    tile[c][px4 + 2] = v.z; tile[c][px4 + 3] = v.w;
  }
  __syncthreads();
  __hip_bfloat16* dst = xt + ((size_t)a * HW + p0) * C;
  int c0  = (tid & 7) * 8;       // channel group
  int pxb = tid >> 3;            // 0..31
#pragma unroll
  for (int i = 0; i < 2; ++i) {
    int px = pxb + 32 * i;
    ushort8 pk;
#pragma unroll
    for (int k = 0; k < 8; ++k) pk[k] = f2bf(tile[c0 + k][px]);
    // lane t -> byte offset 16*t: one contiguous 1KB store per wave-instr
    *reinterpret_cast<ushort8*>(dst + (size_t)px * C + c0) = pk;
  }
}

// Bilinear sample from pixel-major bf16 plane; zero outside bounds
// (clip-then-mask, matching the reference gather). Wave-uniform (ix,iy),
// lane = channel -> each tap is one 128B contiguous load.
__device__ __forceinline__ float bilin_t(const __hip_bfloat16* __restrict__ base,
                                         float ix, float iy, int lane) {
  float x0f = floorf(ix), y0f = floorf(iy);
  float wx = ix - x0f, wy = iy - y0f;
  int x0 = (int)x0f, y0 = (int)y0f;
  int x1 = x0 + 1, y1 = y0 + 1;
  float mx0 = (x0 >= 0 && x0 < W) ? 1.0f : 0.0f;
  float mx1 = (x1 >= 0 && x1 < W) ? 1.0f : 0.0f;
  float my0 = (y0 >= 0 && y0 < H) ? 1.0f : 0.0f;
  float my1 = (y1 >= 0 && y1 < H) ? 1.0f : 0.0f;
  int cx0 = min(max(x0, 0), W - 1);
  int cx1 = min(max(x1, 0), W - 1);
  int cy0 = min(max(y0, 0), H - 1);
  int cy1 = min(max(y1, 0), H - 1);
  float v00 = __bfloat162float(base[((size_t)cy0 * W + cx0) * C + lane]) * (my0 * mx0);
  float v01 = __bfloat162float(base[((size_t)cy0 * W + cx1) * C + lane]) * (my0 * mx1);
  float v10 = __bfloat162float(base[((size_t)cy1 * W + cx0) * C + lane]) * (my1 * mx0);
  float v11 = __bfloat162float(base[((size_t)cy1 * W + cx1) * C + lane]) * (my1 * mx1);
  return v00 * (1.0f - wx) * (1.0f - wy) + v01 * wx * (1.0f - wy)
       + v10 * (1.0f - wx) * wy          + v11 * wx * wy;
}

// ---------------------------------------------------------------------------
// Fused: batch-0 warp+masked-max (agents 0..4 -> lidar/cam bf16, pixel-major)
// and complete batch-1 path (agents 5..9 warp + 5-way self-attn row 0).
// One wave per 8 consecutive pixels, lane = channel.
// ---------------------------------------------------------------------------
__global__ __launch_bounds__(256) void wm_a1(
    const __hip_bfloat16* __restrict__ xt, const float* __restrict__ tmat,
    const int* __restrict__ ind,
    __hip_bfloat16* __restrict__ lidar, __hip_bfloat16* __restrict__ cam,
    float* __restrict__ out) {
  int wid  = (blockIdx.x * 256 + threadIdx.x) >> 6;  // 0..4095
  int lane = threadIdx.x & 63;
  int p0 = wid * 8;
  int h  = p0 >> 8;
  int w0 = p0 & (W - 1);
  float ys = (2.0f * h + 1.0f) / (float)H - 1.0f;

  float o1[8];
#pragma unroll
  for (int i = 0; i < 8; ++i) {
    int p = p0 + i;
    float xs = (2.0f * (w0 + i) + 1.0f) / (float)W - 1.0f;

    // ---- batch 0: warp + masked max over agents 0..4 ----
    float lid = -FLT_MAX, cm = -FLT_MAX;
#pragma unroll
    for (int n = 0; n < 5; ++n) {
      const float* M = tmat + n * 6;                 // pairwise_t_matrix[0,0,n]
      float gx = M[0] * xs + M[1] * ys + M[2];
      float gy = M[3] * xs + M[4] * ys + M[5];
      float ix = ((gx + 1.0f) * (float)W - 1.0f) * 0.5f;
      float iy = ((gy + 1.0f) * (float)H - 1.0f) * 0.5f;
      float v = bilin_t(xt + (size_t)n * HW * C, ix, iy, lane);
      if (ind[n]) lid = fmaxf(lid, v); else cm = fmaxf(cm, v);
    }
    lidar[(size_t)p * C + lane] = __float2bfloat16(lid);
    cam[(size_t)p * C + lane]   = __float2bfloat16(cm);

    // ---- batch 1: warp agents 5..9 + 5-way self-attention (row 0) ----
    float v5[5];
#pragma unroll
    for (int j = 0; j < 5; ++j) {
      const float* M = tmat + (25 + j) * 6;          // pairwise_t_matrix[1,0,j]
      float gx = M[0] * xs + M[1] * ys + M[2];
      float gy = M[3] * xs + M[4] * ys + M[5];
      float ix = ((gx + 1.0f) * (float)W - 1.0f) * 0.5f;
      float iy = ((gy + 1.0f) * (float)H - 1.0f) * 0.5f;
      v5[j] = bilin_t(xt + (size_t)(5 + j) * HW * C, ix, iy, lane);
    }
    float s[5];
#pragma unroll
    for (int j = 0; j < 5; ++j) s[j] = v5[0] * v5[j];
#pragma unroll
    for (int m = 1; m < 64; m <<= 1) {
#pragma unroll
      for (int j = 0; j < 5; ++j) s[j] += __shfl_xor(s[j], m);
    }
#pragma unroll
    for (int j = 0; j < 5; ++j) s[j] *= 0.125f;      // 1/sqrt(64)
    float mx = s[0];
#pragma unroll
    for (int j = 1; j < 5; ++j) mx = fmaxf(mx, s[j]);
    float e[5], sum = 0.0f;
#pragma unroll
    for (int j = 0; j < 5; ++j) { e[j] = __expf(s[j] - mx); sum += e[j]; }
    float inv = 1.0f / sum;
    float o = 0.0f;
#pragma unroll
    for (int j = 0; j < 5; ++j) o += e[j] * inv * v5[j];
    o1[i] = o;
  }

  // coalesced channel-major write: 32B contiguous per lane
  float* ob = out + (size_t)C * HW + (size_t)lane * HW + p0;
  float4 lo = {o1[0], o1[1], o1[2], o1[3]};
  float4 hi = {o1[4], o1[5], o1[6], o1[7]};
  *reinterpret_cast<float4*>(ob)     = lo;
  *reinterpret_cast<float4*>(ob + 4) = hi;
}

// ---------------------------------------------------------------------------
// Batch 0 attention: wave per 8 pixels, lane=channel; 9 keys = (C,H)-rolls
// of cam.  out[0] = max(attn, lidar).
// ---------------------------------------------------------------------------
__global__ __launch_bounds__(256) void attn_b0(
    const __hip_bfloat16* __restrict__ lidar,
    const __hip_bfloat16* __restrict__ cam,
    float* __restrict__ out) {
  int wid  = (blockIdx.x * 256 + threadIdx.x) >> 6;
  int lane = threadIdx.x & 63;
  int p0 = wid * 8;
  int h  = p0 >> 8;
  int w0 = p0 & (W - 1);

  float o0[8];
#pragma unroll
  for (int i = 0; i < 8; ++i) {
    int p = p0 + i;
    int w = w0 + i;
    float q = __bfloat162float(lidar[(size_t)p * C + lane]);

    float row[3];
#pragma unroll
    for (int dyi = 0; dyi < 3; ++dyi) {
      int hh = (h - (dyi - 1) + H) & (H - 1);
      row[dyi] = __bfloat162float(cam[((size_t)hh * W + w) * C + lane]);
    }
    float key[9];
#pragma unroll
    for (int dxi = 0; dxi < 3; ++dxi) {
      int sl = (lane - (dxi - 1)) & 63;
#pragma unroll
      for (int dyi = 0; dyi < 3; ++dyi)
        key[dxi * 3 + dyi] = __shfl(row[dyi], sl);
    }
    float s[9];
#pragma unroll
    for (int r = 0; r < 9; ++r) s[r] = q * key[r];
#pragma unroll
    for (int m = 1; m < 64; m <<= 1) {
#pragma unroll
      for (int r = 0; r < 9; ++r) s[r] += __shfl_xor(s[r], m);
    }
#pragma unroll
    for (int r = 0; r < 9; ++r) s[r] *= 0.125f;
    float mx = s[0];
#pragma unroll
    for (int r = 1; r < 9; ++r) mx = fmaxf(mx, s[r]);
    float e[9], sum = 0.0f;
#pragma unroll
    for (int r = 0; r < 9; ++r) { e[r] = __expf(s[r] - mx); sum += e[r]; }
    float inv = 1.0f / sum;
    float o = 0.0f;
#pragma unroll
    for (int r = 0; r < 9; ++r) o += e[r] * inv * key[r];
    o0[i] = fmaxf(o, q);
  }

  float* ob = out + (size_t)lane * HW + p0;
  float4 lo = {o0[0], o0[1], o0[2], o0[3]};
  float4 hi = {o0[4], o0[5], o0[6], o0[7]};
  *reinterpret_cast<float4*>(ob)     = lo;
  *reinterpret_cast<float4*>(ob + 4) = hi;
}

extern "C" void kernel_launch(void* const* d_in, const int* in_sizes, int n_in,
                              void* d_out, int out_size, void* d_ws, size_t ws_size,
                              hipStream_t stream) {
  const float* x    = (const float*)d_in[0];
  const float* tmat = (const float*)d_in[2];
  const int*   ind  = (const int*)d_in[3];
  float* out = (float*)d_out;

  // ws: xt bf16 [10][HW][64] (41.9MB) | lidar bf16 [HW][64] | cam bf16 [HW][64]
  __hip_bfloat16* xt    = (__hip_bfloat16*)d_ws;
  __hip_bfloat16* lidar = xt + (size_t)10 * HW * C;
  __hip_bfloat16* cam   = lidar + (size_t)HW * C;

  transpose_cp<<<5120, 256, 0, stream>>>(x, xt);
  wm_a1       <<<1024, 256, 0, stream>>>(xt, tmat, ind, lidar, cam, out);
  attn_b0     <<<1024, 256, 0, stream>>>(lidar, cam, out);
}

// Round 4
// 87.230 us; speedup vs baseline: 2.1557x; 2.1557x over previous
//
#include <hip/hip_runtime.h>
#include <hip/hip_bf16.h>
#include <float.h>

// x:(10,64,128,256) f32, record_len=[5,5], pairwise_t_matrix:(2,5,5,2,3) f32,
// indicator:(10,) i32.  Output: (2,64,128,256) f32.
constexpr int C  = 64;
constexpr int H  = 128;
constexpr int W  = 256;
constexpr int HW = H * W;

typedef __attribute__((ext_vector_type(8))) unsigned short ushort8;

__device__ __forceinline__ unsigned short f2bf(float f) {
  __hip_bfloat16 h = __float2bfloat16(f);
  return *reinterpret_cast<unsigned short*>(&h);
}

// ---------------------------------------------------------------------------
// Transpose all 10 agents: x[a][c][p] f32 -> xt[a][p][c] bf16.
// 64ch x 64px tile/block; float4 loads, ushort8 (16B/lane) contiguous stores.
// ---------------------------------------------------------------------------
__global__ __launch_bounds__(256) void transpose_cp(
    const float* __restrict__ x, __hip_bfloat16* __restrict__ xt) {
  __shared__ float tile[64][65];
  int blk = blockIdx.x;          // 0..5119
  int a   = blk >> 9;            // agent 0..9
  int p0  = (blk & 511) << 6;    // pixel base
  int tid = threadIdx.x;
  const float* src = x + (size_t)a * C * HW + p0;
  int row = tid >> 4;            // 0..15
  int px4 = (tid & 15) << 2;     // 0,4,...,60
#pragma unroll
  for (int i = 0; i < 4; ++i) {
    int c = i * 16 + row;
    const float4 v = *reinterpret_cast<const float4*>(src + (size_t)c * HW + px4);
    tile[c][px4 + 0] = v.x; tile[c][px4 + 1] = v.y;
    tile[c][px4 + 2] = v.z; tile[c][px4 + 3] = v.w;
  }
  __syncthreads();
  __hip_bfloat16* dst = xt + ((size_t)a * HW + p0) * C;
  int c0  = (tid & 7) * 8;       // channel group
  int pxb = tid >> 3;            // 0..31
#pragma unroll
  for (int i = 0; i < 2; ++i) {
    int px = pxb + 32 * i;
    ushort8 pk;
#pragma unroll
    for (int k = 0; k < 8; ++k) pk[k] = f2bf(tile[c0 + k][px]);
    *reinterpret_cast<ushort8*>(dst + (size_t)px * C + c0) = pk;
  }
}

// Bilinear sample from pixel-major bf16 plane; zero outside bounds
// (clip-then-mask, matching the reference gather). Wave-uniform (ix,iy),
// lane = channel -> each tap is one 128B contiguous load.
__device__ __forceinline__ float bilin_t(const __hip_bfloat16* __restrict__ base,
                                         float ix, float iy, int lane) {
  float x0f = floorf(ix), y0f = floorf(iy);
  float wx = ix - x0f, wy = iy - y0f;
  int x0 = (int)x0f, y0 = (int)y0f;
  int x1 = x0 + 1, y1 = y0 + 1;
  float mx0 = (x0 >= 0 && x0 < W) ? 1.0f : 0.0f;
  float mx1 = (x1 >= 0 && x1 < W) ? 1.0f : 0.0f;
  float my0 = (y0 >= 0 && y0 < H) ? 1.0f : 0.0f;
  float my1 = (y1 >= 0 && y1 < H) ? 1.0f : 0.0f;
  int cx0 = min(max(x0, 0), W - 1);
  int cx1 = min(max(x1, 0), W - 1);
  int cy0 = min(max(y0, 0), H - 1);
  int cy1 = min(max(y1, 0), H - 1);
  float v00 = __bfloat162float(base[((size_t)cy0 * W + cx0) * C + lane]) * (my0 * mx0);
  float v01 = __bfloat162float(base[((size_t)cy0 * W + cx1) * C + lane]) * (my0 * mx1);
  float v10 = __bfloat162float(base[((size_t)cy1 * W + cx0) * C + lane]) * (my1 * mx0);
  float v11 = __bfloat162float(base[((size_t)cy1 * W + cx1) * C + lane]) * (my1 * mx1);
  return v00 * (1.0f - wx) * (1.0f - wy) + v01 * wx * (1.0f - wy)
       + v10 * (1.0f - wx) * wy          + v11 * wx * wy;
}

// ---------------------------------------------------------------------------
// One launch, two independent jobs (split on wave id), 1 pixel per wave:
//  waves 0..32767   : batch0 warp + masked max -> lidar/cam (bf16 pixel-major)
//  waves 32768..    : batch1 warp agents 5..9 + 5-way self-attn -> out[1]
// ---------------------------------------------------------------------------
__global__ __launch_bounds__(256) void wm_a1_split(
    const __hip_bfloat16* __restrict__ xt, const float* __restrict__ tmat,
    const int* __restrict__ ind,
    __hip_bfloat16* __restrict__ lidar, __hip_bfloat16* __restrict__ cam,
    float* __restrict__ out) {
  int wid  = (blockIdx.x * 256 + threadIdx.x) >> 6;   // 0..65535
  int lane = threadIdx.x & 63;
  int p = wid & (HW - 1);
  int w = p & (W - 1);
  int h = p >> 8;
  float xs = (2.0f * w + 1.0f) / (float)W - 1.0f;
  float ys = (2.0f * h + 1.0f) / (float)H - 1.0f;

  if (wid < HW) {
    // ---- batch 0: warp + masked channelwise max over agents 0..4 ----
    float lid = -FLT_MAX, cm = -FLT_MAX;
#pragma unroll
    for (int n = 0; n < 5; ++n) {
      const float* M = tmat + n * 6;                  // pairwise_t_matrix[0,0,n]
      float gx = M[0] * xs + M[1] * ys + M[2];
      float gy = M[3] * xs + M[4] * ys + M[5];
      float ix = ((gx + 1.0f) * (float)W - 1.0f) * 0.5f;
      float iy = ((gy + 1.0f) * (float)H - 1.0f) * 0.5f;
      float v = bilin_t(xt + (size_t)n * HW * C, ix, iy, lane);
      if (ind[n]) lid = fmaxf(lid, v); else cm = fmaxf(cm, v);
    }
    lidar[(size_t)p * C + lane] = __float2bfloat16(lid);  // 128B coalesced
    cam[(size_t)p * C + lane]   = __float2bfloat16(cm);
  } else {
    // ---- batch 1: warp agents 5..9 + 5-way self-attention (row 0) ----
    float v5[5];
#pragma unroll
    for (int j = 0; j < 5; ++j) {
      const float* M = tmat + (25 + j) * 6;           // pairwise_t_matrix[1,0,j]
      float gx = M[0] * xs + M[1] * ys + M[2];
      float gy = M[3] * xs + M[4] * ys + M[5];
      float ix = ((gx + 1.0f) * (float)W - 1.0f) * 0.5f;
      float iy = ((gy + 1.0f) * (float)H - 1.0f) * 0.5f;
      v5[j] = bilin_t(xt + (size_t)(5 + j) * HW * C, ix, iy, lane);
    }
    float s[5];
#pragma unroll
    for (int j = 0; j < 5; ++j) s[j] = v5[0] * v5[j];
#pragma unroll
    for (int m = 1; m < 64; m <<= 1) {
#pragma unroll
      for (int j = 0; j < 5; ++j) s[j] += __shfl_xor(s[j], m);
    }
#pragma unroll
    for (int j = 0; j < 5; ++j) s[j] *= 0.125f;       // 1/sqrt(64)
    float mx = s[0];
#pragma unroll
    for (int j = 1; j < 5; ++j) mx = fmaxf(mx, s[j]);
    float e[5], sum = 0.0f;
#pragma unroll
    for (int j = 0; j < 5; ++j) { e[j] = __expf(s[j] - mx); sum += e[j]; }
    float inv = 1.0f / sum;
    float o = 0.0f;
#pragma unroll
    for (int j = 0; j < 5; ++j) o += e[j] * inv * v5[j];
    out[(size_t)C * HW + (size_t)lane * HW + p] = o;
  }
}

// ---------------------------------------------------------------------------
// Batch 0 attention: 1 pixel per wave, lane=channel; 9 keys = (C,H)-rolls
// of cam.  out[0] = max(attn, lidar).
// ---------------------------------------------------------------------------
__global__ __launch_bounds__(256) void attn_b0(
    const __hip_bfloat16* __restrict__ lidar,
    const __hip_bfloat16* __restrict__ cam,
    float* __restrict__ out) {
  int p    = (blockIdx.x * 256 + threadIdx.x) >> 6;
  int lane = threadIdx.x & 63;
  int w = p & (W - 1);
  int h = p >> 8;

  float q = __bfloat162float(lidar[(size_t)p * C + lane]);

  float row[3];
#pragma unroll
  for (int dyi = 0; dyi < 3; ++dyi) {
    int hh = (h - (dyi - 1) + H) & (H - 1);
    row[dyi] = __bfloat162float(cam[((size_t)hh * W + w) * C + lane]);
  }
  float key[9];
#pragma unroll
  for (int dxi = 0; dxi < 3; ++dxi) {
    int sl = (lane - (dxi - 1)) & 63;
#pragma unroll
    for (int dyi = 0; dyi < 3; ++dyi)
      key[dxi * 3 + dyi] = __shfl(row[dyi], sl);
  }
  float s[9];
#pragma unroll
  for (int r = 0; r < 9; ++r) s[r] = q * key[r];
#pragma unroll
  for (int m = 1; m < 64; m <<= 1) {
#pragma unroll
    for (int r = 0; r < 9; ++r) s[r] += __shfl_xor(s[r], m);
  }
#pragma unroll
  for (int r = 0; r < 9; ++r) s[r] *= 0.125f;         // 1/sqrt(64)
  float mx = s[0];
#pragma unroll
  for (int r = 1; r < 9; ++r) mx = fmaxf(mx, s[r]);
  float e[9], sum = 0.0f;
#pragma unroll
  for (int r = 0; r < 9; ++r) { e[r] = __expf(s[r] - mx); sum += e[r]; }
  float inv = 1.0f / sum;
  float o = 0.0f;
#pragma unroll
  for (int r = 0; r < 9; ++r) o += e[r] * inv * key[r];

  out[(size_t)lane * HW + p] = fmaxf(o, q);
}

extern "C" void kernel_launch(void* const* d_in, const int* in_sizes, int n_in,
                              void* d_out, int out_size, void* d_ws, size_t ws_size,
                              hipStream_t stream) {
  const float* x    = (const float*)d_in[0];
  const float* tmat = (const float*)d_in[2];
  const int*   ind  = (const int*)d_in[3];
  float* out = (float*)d_out;

  // ws: xt bf16 [10][HW][64] (41.9MB) | lidar bf16 [HW][64] | cam bf16 [HW][64]
  __hip_bfloat16* xt    = (__hip_bfloat16*)d_ws;
  __hip_bfloat16* lidar = xt + (size_t)10 * HW * C;
  __hip_bfloat16* cam   = lidar + (size_t)HW * C;

  transpose_cp<<<5120, 256, 0, stream>>>(x, xt);
  wm_a1_split <<<16384, 256, 0, stream>>>(xt, tmat, ind, lidar, cam, out);
  attn_b0     <<<8192, 256, 0, stream>>>(lidar, cam, out);
}

// Round 5
// 73.412 us; speedup vs baseline: 2.5614x; 1.1882x over previous
//
#include <hip/hip_runtime.h>
#include <hip/hip_bf16.h>
#include <float.h>
#include <stdint.h>

// x:(10,64,128,256) f32, record_len=[5,5], pairwise_t_matrix:(2,5,5,2,3) f32,
// indicator:(10,) i32.  Output: (2,64,128,256) f32.
constexpr int C  = 64;
constexpr int H  = 128;
constexpr int W  = 256;
constexpr int HW = H * W;

typedef __attribute__((ext_vector_type(8))) unsigned short ushort8;

__device__ __forceinline__ unsigned short f2bf(float f) {
  __hip_bfloat16 h = __float2bfloat16(f);
  return *reinterpret_cast<unsigned short*>(&h);
}
__device__ __forceinline__ float bf2f(uint32_t bits16) {   // exact
  uint32_t b = bits16 << 16;
  return __uint_as_float(b);
}

// ---------------------------------------------------------------------------
// Transpose all 10 agents: x[a][c][p] f32 -> xt[a][p][c] bf16.
// ---------------------------------------------------------------------------
__global__ __launch_bounds__(256) void transpose_cp(
    const float* __restrict__ x, __hip_bfloat16* __restrict__ xt) {
  __shared__ float tile[64][65];
  int blk = blockIdx.x;          // 0..5119
  int a   = blk >> 9;            // agent 0..9
  int p0  = (blk & 511) << 6;    // pixel base
  int tid = threadIdx.x;
  const float* src = x + (size_t)a * C * HW + p0;
  int row = tid >> 4;            // 0..15
  int px4 = (tid & 15) << 2;     // 0,4,...,60
#pragma unroll
  for (int i = 0; i < 4; ++i) {
    int c = i * 16 + row;
    const float4 v = *reinterpret_cast<const float4*>(src + (size_t)c * HW + px4);
    tile[c][px4 + 0] = v.x; tile[c][px4 + 1] = v.y;
    tile[c][px4 + 2] = v.z; tile[c][px4 + 3] = v.w;
  }
  __syncthreads();
  __hip_bfloat16* dst = xt + ((size_t)a * HW + p0) * C;
  int c0  = (tid & 7) * 8;       // channel group
  int pxb = tid >> 3;            // 0..31
#pragma unroll
  for (int i = 0; i < 2; ++i) {
    int px = pxb + 32 * i;
    ushort8 pk;
#pragma unroll
    for (int k = 0; k < 8; ++k) pk[k] = f2bf(tile[c0 + k][px]);
    *reinterpret_cast<ushort8*>(dst + (size_t)px * C + c0) = pk;
  }
}

// ---------------------------------------------------------------------------
// Fused warp kernel, 2 pixels per wave:
//   lane&31 = channel-pair (channels 2cl, 2cl+1), lane>>5 = pixel parity.
// Waves 0..16383   : batch0 warp + masked max -> lidar/cam (bf16 [p][c])
// Waves 16384..32767: batch1 warp agents 5..9 + 5-way self-attn -> out[1]
// Phase split: issue all 20 tap loads (ushort2) first, then consume.
// ---------------------------------------------------------------------------
__global__ __launch_bounds__(256, 4) void wm_a1_split2(
    const __hip_bfloat16* __restrict__ xt, const float* __restrict__ tmat,
    const int* __restrict__ ind,
    __hip_bfloat16* __restrict__ lidar, __hip_bfloat16* __restrict__ cam,
    float* __restrict__ out) {
  int wid  = (blockIdx.x * 256 + threadIdx.x) >> 6;   // 0..32767
  int lane = threadIdx.x & 63;
  int half = lane >> 5;            // pixel parity
  int cl   = lane & 31;            // channel pair index
  int job  = wid >> 14;            // 0: batch0 wm, 1: batch1 attn
  int p    = ((wid & 16383) << 1) | half;
  int w = p & (W - 1);
  int h = p >> 8;
  float xs = (2.0f * w + 1.0f) * (1.0f / W) - 1.0f;
  float ys = (2.0f * h + 1.0f) * (1.0f / H) - 1.0f;

  // ---- phase 1: addresses + loads for all 5 agents x 4 taps ----
  uint32_t tv[5][4];   // packed bf16 channel pairs
  float    tw[5][4];   // folded (mask * bilinear) weights, per-lane
#pragma unroll
  for (int n = 0; n < 5; ++n) {
    const float* M = tmat + job * 150 + n * 6;   // [0,0,n] or [1,0,n]
    float gx = M[0] * xs + M[1] * ys + M[2];
    float gy = M[3] * xs + M[4] * ys + M[5];
    float ix = ((gx + 1.0f) * (float)W - 1.0f) * 0.5f;
    float iy = ((gy + 1.0f) * (float)H - 1.0f) * 0.5f;
    float x0f = floorf(ix), y0f = floorf(iy);
    float wx = ix - x0f, wy = iy - y0f;
    int x0 = (int)x0f, y0 = (int)y0f;
    int x1 = x0 + 1, y1 = y0 + 1;
    float mx0 = (x0 >= 0 && x0 < W) ? 1.0f : 0.0f;
    float mx1 = (x1 >= 0 && x1 < W) ? 1.0f : 0.0f;
    float my0 = (y0 >= 0 && y0 < H) ? 1.0f : 0.0f;
    float my1 = (y1 >= 0 && y1 < H) ? 1.0f : 0.0f;
    int cx0 = min(max(x0, 0), W - 1);
    int cx1 = min(max(x1, 0), W - 1);
    int cy0 = min(max(y0, 0), H - 1);
    int cy1 = min(max(y1, 0), H - 1);
    const __hip_bfloat16* base = xt + (size_t)(job * 5 + n) * HW * C + 2 * cl;
    tv[n][0] = *reinterpret_cast<const uint32_t*>(base + ((size_t)cy0 * W + cx0) * C);
    tv[n][1] = *reinterpret_cast<const uint32_t*>(base + ((size_t)cy0 * W + cx1) * C);
    tv[n][2] = *reinterpret_cast<const uint32_t*>(base + ((size_t)cy1 * W + cx0) * C);
    tv[n][3] = *reinterpret_cast<const uint32_t*>(base + ((size_t)cy1 * W + cx1) * C);
    tw[n][0] = (1.0f - wx) * (1.0f - wy) * (mx0 * my0);
    tw[n][1] = wx * (1.0f - wy) * (mx1 * my0);
    tw[n][2] = (1.0f - wx) * wy * (mx0 * my1);
    tw[n][3] = wx * wy * (mx1 * my1);
  }

  // ---- phase 2: consume ----
  if (job == 0) {
    float lx = -FLT_MAX, ly = -FLT_MAX, cx = -FLT_MAX, cy = -FLT_MAX;
#pragma unroll
    for (int n = 0; n < 5; ++n) {
      float vx = 0.0f, vy = 0.0f;
#pragma unroll
      for (int t = 0; t < 4; ++t) {
        vx += bf2f(tv[n][t] & 0xffffu) * tw[n][t];
        vy += bf2f(tv[n][t] >> 16)     * tw[n][t];
      }
      if (ind[n]) { lx = fmaxf(lx, vx); ly = fmaxf(ly, vy); }
      else        { cx = fmaxf(cx, vx); cy = fmaxf(cy, vy); }
    }
    uint32_t lp = (uint32_t)f2bf(lx) | ((uint32_t)f2bf(ly) << 16);
    uint32_t cp = (uint32_t)f2bf(cx) | ((uint32_t)f2bf(cy) << 16);
    // wave writes 2 adjacent pixels' 128B rows -> 256B contiguous
    *reinterpret_cast<uint32_t*>(lidar + (size_t)p * C + 2 * cl) = lp;
    *reinterpret_cast<uint32_t*>(cam   + (size_t)p * C + 2 * cl) = cp;
  } else {
    float vx[5], vy[5];
#pragma unroll
    for (int n = 0; n < 5; ++n) {
      float ax = 0.0f, ay = 0.0f;
#pragma unroll
      for (int t = 0; t < 4; ++t) {
        ax += bf2f(tv[n][t] & 0xffffu) * tw[n][t];
        ay += bf2f(tv[n][t] >> 16)     * tw[n][t];
      }
      vx[n] = ax; vy[n] = ay;
    }
    float s[5];
#pragma unroll
    for (int j = 0; j < 5; ++j) s[j] = vx[0] * vx[j] + vy[0] * vy[j];
#pragma unroll
    for (int m = 1; m < 32; m <<= 1) {   // stays within each 32-lane half
#pragma unroll
      for (int j = 0; j < 5; ++j) s[j] += __shfl_xor(s[j], m);
    }
#pragma unroll
    for (int j = 0; j < 5; ++j) s[j] *= 0.125f;   // 1/sqrt(64)
    float mx = s[0];
#pragma unroll
    for (int j = 1; j < 5; ++j) mx = fmaxf(mx, s[j]);
    float e[5], sum = 0.0f;
#pragma unroll
    for (int j = 0; j < 5; ++j) { e[j] = __expf(s[j] - mx); sum += e[j]; }
    float inv = 1.0f / sum;
    float ox = 0.0f, oy = 0.0f;
#pragma unroll
    for (int j = 0; j < 5; ++j) { ox += e[j] * inv * vx[j]; oy += e[j] * inv * vy[j]; }
    float* ob = out + (size_t)C * HW + (size_t)(2 * cl) * HW + p;
    ob[0]  = ox;
    ob[HW] = oy;
  }
}

// ---------------------------------------------------------------------------
// Batch 0 attention: 1 pixel per wave, lane=channel; 9 keys = (C,H)-rolls
// of cam.  out[0] = max(attn, lidar).
// ---------------------------------------------------------------------------
__global__ __launch_bounds__(256) void attn_b0(
    const __hip_bfloat16* __restrict__ lidar,
    const __hip_bfloat16* __restrict__ cam,
    float* __restrict__ out) {
  int p    = (blockIdx.x * 256 + threadIdx.x) >> 6;
  int lane = threadIdx.x & 63;
  int w = p & (W - 1);
  int h = p >> 8;

  float q = __bfloat162float(lidar[(size_t)p * C + lane]);

  float row[3];
#pragma unroll
  for (int dyi = 0; dyi < 3; ++dyi) {
    int hh = (h - (dyi - 1) + H) & (H - 1);
    row[dyi] = __bfloat162float(cam[((size_t)hh * W + w) * C + lane]);
  }
  float key[9];
#pragma unroll
  for (int dxi = 0; dxi < 3; ++dxi) {
    int sl = (lane - (dxi - 1)) & 63;
#pragma unroll
    for (int dyi = 0; dyi < 3; ++dyi)
      key[dxi * 3 + dyi] = __shfl(row[dyi], sl);
  }
  float s[9];
#pragma unroll
  for (int r = 0; r < 9; ++r) s[r] = q * key[r];
#pragma unroll
  for (int m = 1; m < 64; m <<= 1) {
#pragma unroll
    for (int r = 0; r < 9; ++r) s[r] += __shfl_xor(s[r], m);
  }
#pragma unroll
  for (int r = 0; r < 9; ++r) s[r] *= 0.125f;         // 1/sqrt(64)
  float mx = s[0];
#pragma unroll
  for (int r = 1; r < 9; ++r) mx = fmaxf(mx, s[r]);
  float e[9], sum = 0.0f;
#pragma unroll
  for (int r = 0; r < 9; ++r) { e[r] = __expf(s[r] - mx); sum += e[r]; }
  float inv = 1.0f / sum;
  float o = 0.0f;
#pragma unroll
  for (int r = 0; r < 9; ++r) o += e[r] * inv * key[r];

  out[(size_t)lane * HW + p] = fmaxf(o, q);
}

extern "C" void kernel_launch(void* const* d_in, const int* in_sizes, int n_in,
                              void* d_out, int out_size, void* d_ws, size_t ws_size,
                              hipStream_t stream) {
  const float* x    = (const float*)d_in[0];
  const float* tmat = (const float*)d_in[2];
  const int*   ind  = (const int*)d_in[3];
  float* out = (float*)d_out;

  // ws: xt bf16 [10][HW][64] (41.9MB) | lidar bf16 [HW][64] | cam bf16 [HW][64]
  __hip_bfloat16* xt    = (__hip_bfloat16*)d_ws;
  __hip_bfloat16* lidar = xt + (size_t)10 * HW * C;
  __hip_bfloat16* cam   = lidar + (size_t)HW * C;

  transpose_cp<<<5120, 256, 0, stream>>>(x, xt);
  wm_a1_split2<<<8192, 256, 0, stream>>>(xt, tmat, ind, lidar, cam, out);
  attn_b0     <<<8192, 256, 0, stream>>>(lidar, cam, out);
}

// Round 6
// 62.161 us; speedup vs baseline: 3.0250x; 1.1810x over previous
//
#include <hip/hip_runtime.h>
#include <hip/hip_bf16.h>
#include <float.h>
#include <stdint.h>

// x:(10,64,128,256) f32, record_len=[5,5], pairwise_t_matrix:(2,5,5,2,3) f32,
// indicator:(10,) i32.  Output: (2,64,128,256) f32.
constexpr int C  = 64;
constexpr int H  = 128;
constexpr int W  = 256;
constexpr int HW = H * W;

typedef __attribute__((ext_vector_type(8))) unsigned short ushort8;

__device__ __forceinline__ unsigned short f2bf(float f) {
  __hip_bfloat16 h = __float2bfloat16(f);
  return *reinterpret_cast<unsigned short*>(&h);
}
__device__ __forceinline__ float bf2f(uint32_t bits16) {   // exact
  return __uint_as_float(bits16 << 16);
}

// ---- transpose one 64ch x 64px tile of agent a: x[a][c][p] f32 -> xt[a][p][c] bf16
__device__ __forceinline__ void transpose_tile(
    const float* __restrict__ x, __hip_bfloat16* __restrict__ xt,
    int a, int tblk, int tid) {
  __shared__ float tile[64][65];
  int p0 = (tblk & 511) << 6;
  const float* src = x + (size_t)a * C * HW + p0;
  int row = tid >> 4;            // 0..15
  int px4 = (tid & 15) << 2;     // 0,4,...,60
#pragma unroll
  for (int i = 0; i < 4; ++i) {
    int c = i * 16 + row;
    const float4 v = *reinterpret_cast<const float4*>(src + (size_t)c * HW + px4);
    tile[c][px4 + 0] = v.x; tile[c][px4 + 1] = v.y;
    tile[c][px4 + 2] = v.z; tile[c][px4 + 3] = v.w;
  }
  __syncthreads();
  __hip_bfloat16* dst = xt + ((size_t)a * HW + p0) * C;
  int c0  = (tid & 7) * 8;
  int pxb = tid >> 3;            // 0..31
#pragma unroll
  for (int i = 0; i < 2; ++i) {
    int px = pxb + 32 * i;
    ushort8 pk;
#pragma unroll
    for (int k = 0; k < 8; ++k) pk[k] = f2bf(tile[c0 + k][px]);
    *reinterpret_cast<ushort8*>(dst + (size_t)px * C + c0) = pk;
  }
}

// ---- phase-1 helper: issue 4-tap loads + weights for 5 agents at pixel p.
// lane&31 = channel pair; tv = packed bf16 pairs, tw = mask-folded weights.
__device__ __forceinline__ void gather5(
    const __hip_bfloat16* __restrict__ xt, const float* __restrict__ M5,
    int agent0, int p, int cl, uint32_t tv[5][4], float tw[5][4]) {
  int w = p & (W - 1);
  int h = p >> 8;
  float xs = (2.0f * w + 1.0f) * (1.0f / W) - 1.0f;
  float ys = (2.0f * h + 1.0f) * (1.0f / H) - 1.0f;
#pragma unroll
  for (int n = 0; n < 5; ++n) {
    const float* M = M5 + n * 6;
    float gx = M[0] * xs + M[1] * ys + M[2];
    float gy = M[3] * xs + M[4] * ys + M[5];
    float ix = ((gx + 1.0f) * (float)W - 1.0f) * 0.5f;
    float iy = ((gy + 1.0f) * (float)H - 1.0f) * 0.5f;
    float x0f = floorf(ix), y0f = floorf(iy);
    float wx = ix - x0f, wy = iy - y0f;
    int x0 = (int)x0f, y0 = (int)y0f;
    int x1 = x0 + 1, y1 = y0 + 1;
    float mx0 = (x0 >= 0 && x0 < W) ? 1.0f : 0.0f;
    float mx1 = (x1 >= 0 && x1 < W) ? 1.0f : 0.0f;
    float my0 = (y0 >= 0 && y0 < H) ? 1.0f : 0.0f;
    float my1 = (y1 >= 0 && y1 < H) ? 1.0f : 0.0f;
    int cx0 = min(max(x0, 0), W - 1);
    int cx1 = min(max(x1, 0), W - 1);
    int cy0 = min(max(y0, 0), H - 1);
    int cy1 = min(max(y1, 0), H - 1);
    const __hip_bfloat16* base = xt + (size_t)(agent0 + n) * HW * C + 2 * cl;
    tv[n][0] = *reinterpret_cast<const uint32_t*>(base + ((size_t)cy0 * W + cx0) * C);
    tv[n][1] = *reinterpret_cast<const uint32_t*>(base + ((size_t)cy0 * W + cx1) * C);
    tv[n][2] = *reinterpret_cast<const uint32_t*>(base + ((size_t)cy1 * W + cx0) * C);
    tv[n][3] = *reinterpret_cast<const uint32_t*>(base + ((size_t)cy1 * W + cx1) * C);
    tw[n][0] = (1.0f - wx) * (1.0f - wy) * (mx0 * my0);
    tw[n][1] = wx * (1.0f - wy) * (mx1 * my0);
    tw[n][2] = (1.0f - wx) * wy * (mx0 * my1);
    tw[n][3] = wx * wy * (mx1 * my1);
  }
}

// ---------------------------------------------------------------------------
// K1: transpose agents 0..4 (2560 blocks).
// ---------------------------------------------------------------------------
__global__ __launch_bounds__(256) void k1_t04(
    const float* __restrict__ x, __hip_bfloat16* __restrict__ xt) {
  transpose_tile(x, xt, blockIdx.x >> 9, blockIdx.x, threadIdx.x);
}

// ---------------------------------------------------------------------------
// K2: wm0 (4096 blocks; batch0 warp+masked-max -> lidar/cam) interleaved with
// transpose agents 5..9 (2560 blocks).  Total 6656 blocks.
//  idx<5120: even -> wm(idx/2), odd -> T(idx/2);  idx>=5120 -> wm(idx-2560).
// ---------------------------------------------------------------------------
__global__ __launch_bounds__(256, 4) void k2_wm_t59(
    const float* __restrict__ x, __hip_bfloat16* __restrict__ xt,
    const float* __restrict__ tmat, const int* __restrict__ ind,
    __hip_bfloat16* __restrict__ lidar, __hip_bfloat16* __restrict__ cam) {
  int idx = blockIdx.x;
  bool is_t = (idx < 5120) && (idx & 1);
  if (is_t) {
    int tblk = idx >> 1;                 // 0..2559
    transpose_tile(x, xt, 5 + (tblk >> 9), tblk, threadIdx.x);
    return;
  }
  int wmblk = (idx < 5120) ? (idx >> 1) : (idx - 2560);   // 0..4095
  int wid  = (wmblk * 256 + threadIdx.x) >> 6;            // 0..16383
  int lane = threadIdx.x & 63;
  int half = lane >> 5;
  int cl   = lane & 31;
  int p    = (wid << 1) | half;

  uint32_t tv[5][4];
  float    tw[5][4];
  gather5(xt, tmat, 0, p, cl, tv, tw);    // agents 0..4, pairwise_t_matrix[0,0,n]

  float lx = -FLT_MAX, ly = -FLT_MAX, cx = -FLT_MAX, cy = -FLT_MAX;
#pragma unroll
  for (int n = 0; n < 5; ++n) {
    float vx = 0.0f, vy = 0.0f;
#pragma unroll
    for (int t = 0; t < 4; ++t) {
      vx += bf2f(tv[n][t] & 0xffffu) * tw[n][t];
      vy += bf2f(tv[n][t] >> 16)     * tw[n][t];
    }
    if (ind[n]) { lx = fmaxf(lx, vx); ly = fmaxf(ly, vy); }
    else        { cx = fmaxf(cx, vx); cy = fmaxf(cy, vy); }
  }
  uint32_t lp = (uint32_t)f2bf(lx) | ((uint32_t)f2bf(ly) << 16);
  uint32_t cp = (uint32_t)f2bf(cx) | ((uint32_t)f2bf(cy) << 16);
  *reinterpret_cast<uint32_t*>(lidar + (size_t)p * C + 2 * cl) = lp;
  *reinterpret_cast<uint32_t*>(cam   + (size_t)p * C + 2 * cl) = cp;
}

// ---------------------------------------------------------------------------
// K3: attn_b0 (8192 blocks, 1px/wave) interleaved with a1 (4096 blocks,
// 2px/wave).  Total 12288 blocks; idx%3: 0,1 -> attn, 2 -> a1.
// ---------------------------------------------------------------------------
__global__ __launch_bounds__(256, 4) void k3_attn_a1(
    const __hip_bfloat16* __restrict__ xt, const float* __restrict__ tmat,
    const __hip_bfloat16* __restrict__ lidar,
    const __hip_bfloat16* __restrict__ cam, float* __restrict__ out) {
  int idx = blockIdx.x;
  int r   = idx % 3;
  if (r == 2) {
    // ---- a1: batch1 warp agents 5..9 + 5-way self-attn (row 0) ----
    int bblk = idx / 3;                                   // 0..4095
    int wid  = (bblk * 256 + threadIdx.x) >> 6;           // 0..16383
    int lane = threadIdx.x & 63;
    int half = lane >> 5;
    int cl   = lane & 31;
    int p    = (wid << 1) | half;

    uint32_t tv[5][4];
    float    tw[5][4];
    gather5(xt, tmat + 150, 5, p, cl, tv, tw);  // pairwise_t_matrix[1,0,n]

    float vx[5], vy[5];
#pragma unroll
    for (int n = 0; n < 5; ++n) {
      float ax = 0.0f, ay = 0.0f;
#pragma unroll
      for (int t = 0; t < 4; ++t) {
        ax += bf2f(tv[n][t] & 0xffffu) * tw[n][t];
        ay += bf2f(tv[n][t] >> 16)     * tw[n][t];
      }
      vx[n] = ax; vy[n] = ay;
    }
    float s[5];
#pragma unroll
    for (int j = 0; j < 5; ++j) s[j] = vx[0] * vx[j] + vy[0] * vy[j];
#pragma unroll
    for (int m = 1; m < 32; m <<= 1) {
#pragma unroll
      for (int j = 0; j < 5; ++j) s[j] += __shfl_xor(s[j], m);
    }
#pragma unroll
    for (int j = 0; j < 5; ++j) s[j] *= 0.125f;   // 1/sqrt(64)
    float mx = s[0];
#pragma unroll
    for (int j = 1; j < 5; ++j) mx = fmaxf(mx, s[j]);
    float e[5], sum = 0.0f;
#pragma unroll
    for (int j = 0; j < 5; ++j) { e[j] = __expf(s[j] - mx); sum += e[j]; }
    float inv = 1.0f / sum;
    float ox = 0.0f, oy = 0.0f;
#pragma unroll
    for (int j = 0; j < 5; ++j) { ox += e[j] * inv * vx[j]; oy += e[j] * inv * vy[j]; }
    float* ob = out + (size_t)C * HW + (size_t)(2 * cl) * HW + p;
    ob[0]  = ox;
    ob[HW] = oy;
  } else {
    // ---- attn_b0: 1px/wave, lane=channel; 9 keys = (C,H)-rolls of cam ----
    int ablk = 2 * (idx / 3) + r;                         // 0..8191
    int p    = (ablk * 256 + (int)threadIdx.x) >> 6;      // 0..32767
    int lane = threadIdx.x & 63;
    int w = p & (W - 1);
    int h = p >> 8;

    float q = __bfloat162float(lidar[(size_t)p * C + lane]);

    float row[3];
#pragma unroll
    for (int dyi = 0; dyi < 3; ++dyi) {
      int hh = (h - (dyi - 1) + H) & (H - 1);
      row[dyi] = __bfloat162float(cam[((size_t)hh * W + w) * C + lane]);
    }
    float key[9];
#pragma unroll
    for (int dxi = 0; dxi < 3; ++dxi) {
      int sl = (lane - (dxi - 1)) & 63;
#pragma unroll
      for (int dyi = 0; dyi < 3; ++dyi)
        key[dxi * 3 + dyi] = __shfl(row[dyi], sl);
    }
    float s[9];
#pragma unroll
    for (int rr = 0; rr < 9; ++rr) s[rr] = q * key[rr];
#pragma unroll
    for (int m = 1; m < 64; m <<= 1) {
#pragma unroll
      for (int rr = 0; rr < 9; ++rr) s[rr] += __shfl_xor(s[rr], m);
    }
#pragma unroll
    for (int rr = 0; rr < 9; ++rr) s[rr] *= 0.125f;       // 1/sqrt(64)
    float mx = s[0];
#pragma unroll
    for (int rr = 1; rr < 9; ++rr) mx = fmaxf(mx, s[rr]);
    float e[9], sum = 0.0f;
#pragma unroll
    for (int rr = 0; rr < 9; ++rr) { e[rr] = __expf(s[rr] - mx); sum += e[rr]; }
    float inv = 1.0f / sum;
    float o = 0.0f;
#pragma unroll
    for (int rr = 0; rr < 9; ++rr) o += e[rr] * inv * key[rr];

    out[(size_t)lane * HW + p] = fmaxf(o, q);
  }
}

extern "C" void kernel_launch(void* const* d_in, const int* in_sizes, int n_in,
                              void* d_out, int out_size, void* d_ws, size_t ws_size,
                              hipStream_t stream) {
  const float* x    = (const float*)d_in[0];
  const float* tmat = (const float*)d_in[2];
  const int*   ind  = (const int*)d_in[3];
  float* out = (float*)d_out;

  // ws: xt bf16 [10][HW][64] (41.9MB) | lidar bf16 [HW][64] | cam bf16 [HW][64]
  __hip_bfloat16* xt    = (__hip_bfloat16*)d_ws;
  __hip_bfloat16* lidar = xt + (size_t)10 * HW * C;
  __hip_bfloat16* cam   = lidar + (size_t)HW * C;

  k1_t04    <<<2560, 256, 0, stream>>>(x, xt);
  k2_wm_t59 <<<6656, 256, 0, stream>>>(x, xt, tmat, ind, lidar, cam);
  k3_attn_a1<<<12288, 256, 0, stream>>>(xt, tmat, lidar, cam, out);
}

// Round 7
// 51.825 us; speedup vs baseline: 3.6284x; 1.1994x over previous
//
#include <hip/hip_runtime.h>
#include <hip/hip_bf16.h>
#include <float.h>
#include <stdint.h>

// x:(10,64,128,256) f32, record_len=[5,5], pairwise_t_matrix:(2,5,5,2,3) f32,
// indicator:(10,) i32.  Output: (2,64,128,256) f32.
constexpr int C  = 64;
constexpr int H  = 128;
constexpr int W  = 256;
constexpr int HW = H * W;

typedef __attribute__((ext_vector_type(8))) unsigned short ushort8;
typedef __attribute__((ext_vector_type(4))) unsigned short ushort4v;

__device__ __forceinline__ unsigned short f2bf(float f) {
  __hip_bfloat16 h = __float2bfloat16(f);
  return *reinterpret_cast<unsigned short*>(&h);
}
__device__ __forceinline__ float bf2f(uint32_t bits16) {   // exact
  return __uint_as_float(bits16 << 16);
}

// ---- transpose one 64ch x 64px tile of agent a: x[a][c][p] f32 -> xt[a][p][c] bf16
__device__ __forceinline__ void transpose_tile(
    const float* __restrict__ x, __hip_bfloat16* __restrict__ xt,
    int a, int tblk, int tid) {
  __shared__ float tile[64][65];
  int p0 = (tblk & 511) << 6;
  const float* src = x + (size_t)a * C * HW + p0;
  int row = tid >> 4;            // 0..15
  int px4 = (tid & 15) << 2;     // 0,4,...,60
#pragma unroll
  for (int i = 0; i < 4; ++i) {
    int c = i * 16 + row;
    const float4 v = *reinterpret_cast<const float4*>(src + (size_t)c * HW + px4);
    tile[c][px4 + 0] = v.x; tile[c][px4 + 1] = v.y;
    tile[c][px4 + 2] = v.z; tile[c][px4 + 3] = v.w;
  }
  __syncthreads();
  __hip_bfloat16* dst = xt + ((size_t)a * HW + p0) * C;
  int c0  = (tid & 7) * 8;
  int pxb = tid >> 3;            // 0..31
#pragma unroll
  for (int i = 0; i < 2; ++i) {
    int px = pxb + 32 * i;
    ushort8 pk;
#pragma unroll
    for (int k = 0; k < 8; ++k) pk[k] = f2bf(tile[c0 + k][px]);
    *reinterpret_cast<ushort8*>(dst + (size_t)px * C + c0) = pk;
  }
}

// ---- phase-1 helper (quad version): issue 4-tap ushort4 loads + weights for
// 5 agents at pixel p.  cq = 4-channel group (channels 4cq..4cq+3).
__device__ __forceinline__ void gather5q(
    const __hip_bfloat16* __restrict__ xt, const float* __restrict__ M5,
    int agent0, int p, int cq, ushort4v tv[5][4], float tw[5][4]) {
  int w = p & (W - 1);
  int h = p >> 8;
  float xs = (2.0f * w + 1.0f) * (1.0f / W) - 1.0f;
  float ys = (2.0f * h + 1.0f) * (1.0f / H) - 1.0f;
#pragma unroll
  for (int n = 0; n < 5; ++n) {
    const float* M = M5 + n * 6;
    float gx = M[0] * xs + M[1] * ys + M[2];
    float gy = M[3] * xs + M[4] * ys + M[5];
    float ix = ((gx + 1.0f) * (float)W - 1.0f) * 0.5f;
    float iy = ((gy + 1.0f) * (float)H - 1.0f) * 0.5f;
    float x0f = floorf(ix), y0f = floorf(iy);
    float wx = ix - x0f, wy = iy - y0f;
    int x0 = (int)x0f, y0 = (int)y0f;
    int x1 = x0 + 1, y1 = y0 + 1;
    float mx0 = (x0 >= 0 && x0 < W) ? 1.0f : 0.0f;
    float mx1 = (x1 >= 0 && x1 < W) ? 1.0f : 0.0f;
    float my0 = (y0 >= 0 && y0 < H) ? 1.0f : 0.0f;
    float my1 = (y1 >= 0 && y1 < H) ? 1.0f : 0.0f;
    int cx0 = min(max(x0, 0), W - 1);
    int cx1 = min(max(x1, 0), W - 1);
    int cy0 = min(max(y0, 0), H - 1);
    int cy1 = min(max(y1, 0), H - 1);
    const __hip_bfloat16* base = xt + (size_t)(agent0 + n) * HW * C + 4 * cq;
    tv[n][0] = *reinterpret_cast<const ushort4v*>(base + ((size_t)cy0 * W + cx0) * C);
    tv[n][1] = *reinterpret_cast<const ushort4v*>(base + ((size_t)cy0 * W + cx1) * C);
    tv[n][2] = *reinterpret_cast<const ushort4v*>(base + ((size_t)cy1 * W + cx0) * C);
    tv[n][3] = *reinterpret_cast<const ushort4v*>(base + ((size_t)cy1 * W + cx1) * C);
    tw[n][0] = (1.0f - wx) * (1.0f - wy) * (mx0 * my0);
    tw[n][1] = wx * (1.0f - wy) * (mx1 * my0);
    tw[n][2] = (1.0f - wx) * wy * (mx0 * my1);
    tw[n][3] = wx * wy * (mx1 * my1);
  }
}

// ---------------------------------------------------------------------------
// K1: transpose agents 0..4 (2560 blocks).
// ---------------------------------------------------------------------------
__global__ __launch_bounds__(256) void k1_t04(
    const float* __restrict__ x, __hip_bfloat16* __restrict__ xt) {
  transpose_tile(x, xt, blockIdx.x >> 9, blockIdx.x, threadIdx.x);
}

// ---------------------------------------------------------------------------
// K2: wm0 quads (2048 blocks; 4px/wave) interleaved with transpose agents
// 5..9 (2560 blocks).  Grid 4608 = 512*9; idx%9: 0..3 -> wm, 4..8 -> T.
// ---------------------------------------------------------------------------
__global__ __launch_bounds__(256, 4) void k2_wm_t59(
    const float* __restrict__ x, __hip_bfloat16* __restrict__ xt,
    const float* __restrict__ tmat, const int* __restrict__ ind,
    __hip_bfloat16* __restrict__ lidar, __hip_bfloat16* __restrict__ cam) {
  int idx = blockIdx.x;
  int k = idx / 9, r = idx % 9;
  if (r >= 4) {
    int tblk = 5 * k + (r - 4);          // 0..2559
    transpose_tile(x, xt, 5 + (tblk >> 9), tblk, threadIdx.x);
    return;
  }
  int wmblk = 4 * k + r;                               // 0..2047
  int wid  = (wmblk * 256 + (int)threadIdx.x) >> 6;    // 0..8191
  int lane = threadIdx.x & 63;
  int cq = lane & 15;                  // channel quad
  int pi = lane >> 4;                  // pixel 0..3 within wave
  int p  = (wid << 2) | pi;

  ushort4v tv[5][4];
  float    tw[5][4];
  gather5q(xt, tmat, 0, p, cq, tv, tw);   // agents 0..4, pairwise_t_matrix[0,0,n]

  float lid[4] = {-FLT_MAX, -FLT_MAX, -FLT_MAX, -FLT_MAX};
  float cm[4]  = {-FLT_MAX, -FLT_MAX, -FLT_MAX, -FLT_MAX};
#pragma unroll
  for (int n = 0; n < 5; ++n) {
    float v[4] = {0.0f, 0.0f, 0.0f, 0.0f};
#pragma unroll
    for (int t = 0; t < 4; ++t) {
      float wgt = tw[n][t];
#pragma unroll
      for (int c = 0; c < 4; ++c)
        v[c] += bf2f((uint32_t)tv[n][t][c]) * wgt;
    }
    if (ind[n]) {
#pragma unroll
      for (int c = 0; c < 4; ++c) lid[c] = fmaxf(lid[c], v[c]);
    } else {
#pragma unroll
      for (int c = 0; c < 4; ++c) cm[c] = fmaxf(cm[c], v[c]);
    }
  }
  ushort4v lp, cp;
#pragma unroll
  for (int c = 0; c < 4; ++c) { lp[c] = f2bf(lid[c]); cp[c] = f2bf(cm[c]); }
  *reinterpret_cast<ushort4v*>(lidar + (size_t)p * C + 4 * cq) = lp;
  *reinterpret_cast<ushort4v*>(cam   + (size_t)p * C + 4 * cq) = cp;
}

// ---------------------------------------------------------------------------
// K3: attn_b0 pairs (4096 blocks, 2px/wave) interleaved with a1 quads
// (2048 blocks, 4px/wave).  Grid 6144; idx%3: 0,1 -> attn, 2 -> a1.
// ---------------------------------------------------------------------------
__global__ __launch_bounds__(256, 4) void k3_attn_a1(
    const __hip_bfloat16* __restrict__ xt, const float* __restrict__ tmat,
    const __hip_bfloat16* __restrict__ lidar,
    const __hip_bfloat16* __restrict__ cam, float* __restrict__ out) {
  int idx = blockIdx.x;
  int r   = idx % 3;
  if (r == 2) {
    // ---- a1: batch1 warp agents 5..9 + 5-way self-attn (row 0), quads ----
    int bblk = idx / 3;                                   // 0..2047
    int wid  = (bblk * 256 + (int)threadIdx.x) >> 6;      // 0..8191
    int lane = threadIdx.x & 63;
    int cq = lane & 15;
    int pi = lane >> 4;
    int p  = (wid << 2) | pi;

    ushort4v tv[5][4];
    float    tw[5][4];
    gather5q(xt, tmat + 150, 5, p, cq, tv, tw);  // pairwise_t_matrix[1,0,n]

    float vx[5][4];
#pragma unroll
    for (int n = 0; n < 5; ++n) {
#pragma unroll
      for (int c = 0; c < 4; ++c) vx[n][c] = 0.0f;
#pragma unroll
      for (int t = 0; t < 4; ++t) {
        float wgt = tw[n][t];
#pragma unroll
        for (int c = 0; c < 4; ++c)
          vx[n][c] += bf2f((uint32_t)tv[n][t][c]) * wgt;
      }
    }
    float s[5];
#pragma unroll
    for (int j = 0; j < 5; ++j) {
      s[j] = vx[0][0] * vx[j][0] + vx[0][1] * vx[j][1]
           + vx[0][2] * vx[j][2] + vx[0][3] * vx[j][3];
    }
#pragma unroll
    for (int m = 1; m < 16; m <<= 1) {   // reduce across 16-lane channel groups
#pragma unroll
      for (int j = 0; j < 5; ++j) s[j] += __shfl_xor(s[j], m);
    }
#pragma unroll
    for (int j = 0; j < 5; ++j) s[j] *= 0.125f;   // 1/sqrt(64)
    float mx = s[0];
#pragma unroll
    for (int j = 1; j < 5; ++j) mx = fmaxf(mx, s[j]);
    float e[5], sum = 0.0f;
#pragma unroll
    for (int j = 0; j < 5; ++j) { e[j] = __expf(s[j] - mx); sum += e[j]; }
    float inv = 1.0f / sum;
    float* ob = out + (size_t)C * HW + (size_t)(4 * cq) * HW + p;
#pragma unroll
    for (int c = 0; c < 4; ++c) {
      float o = 0.0f;
#pragma unroll
      for (int j = 0; j < 5; ++j) o += e[j] * inv * vx[j][c];
      ob[(size_t)c * HW] = o;
    }
  } else {
    // ---- attn_b0: 2px/wave, channel pairs; 9 keys = (C,H)-rolls of cam ----
    int ablk = 2 * (idx / 3) + r;                         // 0..4095
    int wid  = (ablk * 256 + (int)threadIdx.x) >> 6;      // 0..16383
    int lane = threadIdx.x & 63;
    int half = lane >> 5;
    int cl   = lane & 31;                                 // channel pair
    int p    = (wid << 1) | half;
    int w = p & (W - 1);
    int h = p >> 8;

    uint32_t qpk = *reinterpret_cast<const uint32_t*>(lidar + (size_t)p * C + 2 * cl);
    float q0 = bf2f(qpk & 0xffffu), q1 = bf2f(qpk >> 16);

    uint32_t rowpk[3];
#pragma unroll
    for (int dyi = 0; dyi < 3; ++dyi) {
      int hh = (h - (dyi - 1) + H) & (H - 1);
      rowpk[dyi] = *reinterpret_cast<const uint32_t*>(cam + ((size_t)hh * W + w) * C + 2 * cl);
    }
    int lprev = (half << 5) | ((cl - 1) & 31);
    int lnext = (half << 5) | ((cl + 1) & 31);

    // key[r = dxi*3+dyi], packed as (ch 2cl lo, ch 2cl+1 hi) after roll dx
    uint32_t key[9];
#pragma unroll
    for (int dyi = 0; dyi < 3; ++dyi) {
      uint32_t cur  = rowpk[dyi];
      uint32_t prev = (uint32_t)__shfl((int)cur, lprev);
      uint32_t next = (uint32_t)__shfl((int)cur, lnext);
      key[0 * 3 + dyi] = (cur >> 16) | (next << 16);  // dx=-1: ch (2cl+1, 2cl+2)
      key[1 * 3 + dyi] = cur;                          // dx= 0
      key[2 * 3 + dyi] = (prev >> 16) | (cur << 16);   // dx=+1: ch (2cl-1, 2cl)
    }
    float s[9];
#pragma unroll
    for (int rr = 0; rr < 9; ++rr)
      s[rr] = q0 * bf2f(key[rr] & 0xffffu) + q1 * bf2f(key[rr] >> 16);
#pragma unroll
    for (int m = 1; m < 32; m <<= 1) {   // reduce across 32-lane half
#pragma unroll
      for (int rr = 0; rr < 9; ++rr) s[rr] += __shfl_xor(s[rr], m);
    }
#pragma unroll
    for (int rr = 0; rr < 9; ++rr) s[rr] *= 0.125f;       // 1/sqrt(64)
    float mx = s[0];
#pragma unroll
    for (int rr = 1; rr < 9; ++rr) mx = fmaxf(mx, s[rr]);
    float e[9], sum = 0.0f;
#pragma unroll
    for (int rr = 0; rr < 9; ++rr) { e[rr] = __expf(s[rr] - mx); sum += e[rr]; }
    float inv = 1.0f / sum;
    float o0 = 0.0f, o1 = 0.0f;
#pragma unroll
    for (int rr = 0; rr < 9; ++rr) {
      float a = e[rr] * inv;
      o0 += a * bf2f(key[rr] & 0xffffu);
      o1 += a * bf2f(key[rr] >> 16);
    }
    out[(size_t)(2 * cl + 0) * HW + p] = fmaxf(o0, q0);
    out[(size_t)(2 * cl + 1) * HW + p] = fmaxf(o1, q1);
  }
}

extern "C" void kernel_launch(void* const* d_in, const int* in_sizes, int n_in,
                              void* d_out, int out_size, void* d_ws, size_t ws_size,
                              hipStream_t stream) {
  const float* x    = (const float*)d_in[0];
  const float* tmat = (const float*)d_in[2];
  const int*   ind  = (const int*)d_in[3];
  float* out = (float*)d_out;

  // ws: xt bf16 [10][HW][64] (41.9MB) | lidar bf16 [HW][64] | cam bf16 [HW][64]
  __hip_bfloat16* xt    = (__hip_bfloat16*)d_ws;
  __hip_bfloat16* lidar = xt + (size_t)10 * HW * C;
  __hip_bfloat16* cam   = lidar + (size_t)HW * C;

  k1_t04    <<<2560, 256, 0, stream>>>(x, xt);
  k2_wm_t59 <<<4608, 256, 0, stream>>>(x, xt, tmat, ind, lidar, cam);
  k3_attn_a1<<<6144, 256, 0, stream>>>(xt, tmat, lidar, cam, out);
}